// Round 5
// baseline (510.427 us; speedup 1.0000x reference)
//
#include <hip/hip_runtime.h>
#include <stdint.h>

typedef unsigned short ushort_t;
typedef float f32x2 __attribute__((ext_vector_type(2)));
typedef float f32x4 __attribute__((ext_vector_type(4)));
typedef float f32x16 __attribute__((ext_vector_type(16)));
typedef short bf16x8 __attribute__((ext_vector_type(8)));
typedef unsigned short us8 __attribute__((ext_vector_type(8)));

#define BATCH 8
#define SEQ   2048
#define DIM   512
#define NIT   32        // 64 keys per iteration

__device__ __forceinline__ ushort_t f2bf(float f) {
  union { float f; uint32_t u; } c; c.f = f;
  return (ushort_t)((c.u + 0x7FFFu + ((c.u >> 16) & 1u)) >> 16);  // RNE
}

// ---------------- k_prep ----------------
// Per block: one 32-row strip. Outputs:
//  kg: normalized*sqrt(log2e), A-frag layout  [strip][ks=d/16][32 k][16 d]
//  vg: raw bf16,               B-frag layout  [b][kblk=k/16][dblk=d/32][32 d][16 k]
__global__ __launch_bounds__(256) void k_prep(const float* __restrict__ x,
                                              ushort_t* __restrict__ kg,
                                              ushort_t* __restrict__ vg) {
  __shared__ ushort_t ln[32 * 512];   // normalized, chunk-swizzled: slot = c ^ row
  __shared__ ushort_t rw[32 * 512];   // raw,        chunk-swizzled
  const int tid = threadIdx.x, lane = tid & 63, w = tid >> 6;
  const int bs = blockIdx.x;                 // global strip 0..511
  const int b = bs >> 6, sib = bs & 63;
  const float* xs = x + (size_t)bs * 32 * DIM;
  ushort_t* kgs = kg + (size_t)bs * 32 * DIM;
  ushort_t* vgb = vg + (size_t)b * SEQ * DIM;

#pragma unroll
  for (int j = 0; j < 8; ++j) {
    const int rl = w * 8 + j;
    const float4 a = *(const float4*)(xs + (size_t)rl * DIM + lane * 8);
    const float4 c = *(const float4*)(xs + (size_t)rl * DIM + lane * 8 + 4);
    float ss = a.x*a.x + a.y*a.y + a.z*a.z + a.w*a.w
             + c.x*c.x + c.y*c.y + c.z*c.z + c.w*c.w;
#pragma unroll
    for (int m = 32; m >= 1; m >>= 1) ss += __shfl_xor(ss, m, 64);
    const float rn = 1.2011224087864498f / sqrtf(fmaxf(ss, 1e-24f));
    us8 nv, rv;
    nv[0]=f2bf(a.x*rn); nv[1]=f2bf(a.y*rn); nv[2]=f2bf(a.z*rn); nv[3]=f2bf(a.w*rn);
    nv[4]=f2bf(c.x*rn); nv[5]=f2bf(c.y*rn); nv[6]=f2bf(c.z*rn); nv[7]=f2bf(c.w*rn);
    rv[0]=f2bf(a.x); rv[1]=f2bf(a.y); rv[2]=f2bf(a.z); rv[3]=f2bf(a.w);
    rv[4]=f2bf(c.x); rv[5]=f2bf(c.y); rv[6]=f2bf(c.z); rv[7]=f2bf(c.w);
    *(us8*)(&ln[rl * 512 + ((lane ^ rl) << 3)]) = nv;
    *(us8*)(&rw[rl * 512 + ((lane ^ rl) << 3)]) = rv;
  }
  __syncthreads();

  const int k32 = tid & 31, g = tid >> 5;
  // kg: block ks holds [32 k][16 d], row k32 = 32B (chunks 2ks, 2ks+1)
#pragma unroll
  for (int p = 0; p < 4; ++p) {
    const int ks = p * 8 + g;
    const us8 e0 = *(const us8*)(&ln[k32 * 512 + (((2 * ks)     ^ k32) << 3)]);
    const us8 e1 = *(const us8*)(&ln[k32 * 512 + (((2 * ks + 1) ^ k32) << 3)]);
    *(us8*)(kgs + ks * 512 + k32 * 16)     = e0;
    *(us8*)(kgs + ks * 512 + k32 * 16 + 8) = e1;
  }
  // vg: block (kh,db) holds [32 d][16 k]; gather along k from rw
#pragma unroll
  for (int p = 0; p < 4; ++p) {
    const int blk = p * 8 + g;            // 0..31
    const int kh = blk >> 4, db = blk & 15;
    const int cch = db * 4 + (k32 >> 3);  // k32 doubles as d32 here
    us8 v0, v1;
#pragma unroll
    for (int j = 0; j < 8; ++j) {
      const int ka = kh * 16 + j;
      const int kb = kh * 16 + 8 + j;
      v0[j] = rw[ka * 512 + ((cch ^ ka) << 3) + (k32 & 7)];
      v1[j] = rw[kb * 512 + ((cch ^ kb) << 3) + (k32 & 7)];
    }
    ushort_t* dst = vgb + ((size_t)(sib * 2 + kh) * 16 + db) * 512 + k32 * 16;
    *(us8*)(dst)     = v0;
    *(us8*)(dst + 8) = v1;
  }
}

// ---------------- k_attn ----------------
// 256 blocks (b=bid&7 XCD-affine, qt0=bid>>3), 512 thr = 8 waves.
// Waves 0-3: QK producers (kw=w&1 key-half, kd=(w>>1)&1 d-half), Sp exchange.
// Waves 4-7: PV consumers (jv d-slice of 128) + softmax finalize + epilogue.
// All MFMA operands except Q/P stream from L2 via MFMA-native global layouts,
// register-pipelined one iteration ahead. 2 barriers/iter, no vmcnt drains.
#define LSP   65536
#define LP0   98304
#define LP1   106496
#define LRED  114688
#define LDS_TOTAL 115712

__global__ __launch_bounds__(512, 2) void k_attn(const ushort_t* __restrict__ kg,
                                                 const ushort_t* __restrict__ vg,
                                                 const float* __restrict__ x,
                                                 float* __restrict__ out) {
  extern __shared__ char smem[];
  ushort_t* const Qs = (ushort_t*)smem;            // [64 q][512 d], slot = c ^ (q&31)
  float* const Sp = (float*)(smem + LSP);          // 4 tiles [64 q][32 k], slot8B ^ (q&15)
  float* const lred = (float*)(smem + LRED);

  const int tid = threadIdx.x, lane = tid & 63, w = tid >> 6;
  const int l31 = lane & 31, l5 = lane >> 5;
  const int b = blockIdx.x & 7, qt0 = blockIdx.x >> 3;
  const ushort_t* kgb = kg + (size_t)b * SEQ * DIM;
  const ushort_t* vgb = vg + (size_t)b * SEQ * DIM;

  // ---- prologue: stage Qs from kg (swizzled dst; one-time) ----
  {
    const int r = tid >> 3;
    const size_t strip = (size_t)(qt0 * 2 + (r >> 5));
#pragma unroll
    for (int it = 0; it < 8; ++it) {
      const int s = it * 8 + (tid & 7);       // dst slot
      const int c = s ^ (r & 31);             // content chunk
      const bf16x8 v = *(const bf16x8*)(kgb + strip * 16384
                          + (c >> 1) * 512 + (r & 31) * 16 + (c & 1) * 8);
      *(bf16x8*)(Qs + r * 512 + s * 8) = v;
    }
  }
  const bool isQK = (w < 4);
  const int kw = w & 1, kd = (w >> 1) & 1;   // QK role
  const int jv = w - 4;                       // PV role

  bf16x8 acur[16];
  bf16x8 vcur[16];
  f32x16 acc[2][4];
  float plsum = 0.f;

  if (isQK) {
#pragma unroll
    for (int ks = 0; ks < 16; ++ks)
      acur[ks] = *(const bf16x8*)(kgb + (size_t)kw * 16384
                    + (kd * 16 + ks) * 512 + l31 * 16 + l5 * 8);
  } else {
    const f32x16 z = {};
#pragma unroll
    for (int qt = 0; qt < 2; ++qt)
#pragma unroll
      for (int dt = 0; dt < 4; ++dt) acc[qt][dt] = z;
  }
  asm volatile("s_waitcnt lgkmcnt(0)" ::: "memory");
  __builtin_amdgcn_s_barrier();
  __builtin_amdgcn_sched_barrier(0);

  for (int t = 0; t < NIT; ++t) {
    char* const Pprev = smem + ((t & 1) ? LP0 : LP1);   // tile t-1
    char* const Pcur  = smem + ((t & 1) ? LP1 : LP0);   // tile t

    if (isQK) {
      const int tn = (t + 1 < NIT) ? (t + 1) : t;
      const ushort_t* abase = kgb + (size_t)(2 * tn + kw) * 16384;
      f32x16 s0 = {}, s1 = {};
#pragma unroll
      for (int ks = 0; ks < 16; ++ks) {
        const int cc = kd * 32 + ks * 2 + l5;
        const bf16x8 b0 = *(const bf16x8*)(Qs + l31 * 512 + ((cc ^ l31) << 3));
        const bf16x8 b1 = *(const bf16x8*)(Qs + (32 + l31) * 512 + ((cc ^ l31) << 3));
        s0 = __builtin_amdgcn_mfma_f32_32x32x16_bf16(acur[ks], b0, s0, 0, 0, 0);
        s1 = __builtin_amdgcn_mfma_f32_32x32x16_bf16(acur[ks], b1, s1, 0, 0, 0);
        acur[ks] = *(const bf16x8*)(abase + (kd * 16 + ks) * 512 + l31 * 16 + l5 * 8);
      }
      float* const sw = Sp + (kw * 2 + kd) * 2048;
#pragma unroll
      for (int qt = 0; qt < 2; ++qt) {
        const int q = qt * 32 + l31;
        const f32x16 sv = qt ? s1 : s0;
#pragma unroll
        for (int mm = 0; mm < 4; ++mm) {
          const int u0 = 4 * mm + 2 * l5;
          const f32x2 p0 = { sv[4 * mm],     sv[4 * mm + 1] };
          const f32x2 p1 = { sv[4 * mm + 2], sv[4 * mm + 3] };
          *(f32x2*)(sw + q * 32 + ((u0 ^ (l31 & 15)) << 1))       = p0;
          *(f32x2*)(sw + q * 32 + (((u0 + 1) ^ (l31 & 15)) << 1)) = p1;
        }
      }
      asm volatile("s_waitcnt lgkmcnt(0)" ::: "memory");
      __builtin_amdgcn_sched_barrier(0);
    } else {
      if (t > 0) {
#pragma unroll
        for (int qt = 0; qt < 2; ++qt)
#pragma unroll
          for (int ks = 0; ks < 4; ++ks) {
            const bf16x8 pa = *(const bf16x8*)(Pprev + (qt * 32 + l31) * 128
                                + (((ks * 2 + l5) ^ (l31 & 7)) << 4));
#pragma unroll
            for (int dt = 0; dt < 4; ++dt)
              acc[qt][dt] = __builtin_amdgcn_mfma_f32_32x32x16_bf16(
                  pa, vcur[dt * 4 + ks], acc[qt][dt], 0, 0, 0);
          }
      }
#pragma unroll
      for (int dt = 0; dt < 4; ++dt)
#pragma unroll
        for (int ks = 0; ks < 4; ++ks)
          vcur[dt * 4 + ks] = *(const bf16x8*)(vgb
              + ((size_t)(t * 4 + ks) * 16 + jv * 4 + dt) * 512 + l31 * 16 + l5 * 8);
    }
    __builtin_amdgcn_s_barrier();          // BAR A: Sp(t) ready; P(t-1) reads done
    __builtin_amdgcn_sched_barrier(0);

    if (!isQK) {
      // finalize tile t for key strip jv*16..+16 (lane = q row)
      const float* sr0 = Sp + ((jv >> 1) * 2 + 0) * 2048 + lane * 32;
      const float* sr1 = Sp + ((jv >> 1) * 2 + 1) * 2048 + lane * 32;
      float pv[16];
#pragma unroll
      for (int m2 = 0; m2 < 8; ++m2) {
        const int u = (((jv & 1) * 8 + m2) ^ (lane & 15)) << 1;
        const f32x2 a0 = *(const f32x2*)(sr0 + u);
        const f32x2 a1 = *(const f32x2*)(sr1 + u);
        pv[2 * m2]     = __builtin_amdgcn_exp2f(a0[0] + a1[0]);
        pv[2 * m2 + 1] = __builtin_amdgcn_exp2f(a0[1] + a1[1]);
      }
      us8 w0, w1;
#pragma unroll
      for (int m = 0; m < 8; ++m) {
        w0[m] = f2bf(pv[m]); w1[m] = f2bf(pv[8 + m]);
        plsum += pv[m] + pv[8 + m];
      }
      *(us8*)(Pcur + lane * 128 + (((jv * 2)     ^ (lane & 7)) << 4)) = w0;
      *(us8*)(Pcur + lane * 128 + (((jv * 2 + 1) ^ (lane & 7)) << 4)) = w1;
      asm volatile("s_waitcnt lgkmcnt(0)" ::: "memory");
      __builtin_amdgcn_sched_barrier(0);
    }
    __builtin_amdgcn_s_barrier();          // BAR B: P(t) ready
    __builtin_amdgcn_sched_barrier(0);
  }

  // ---- epilogue ----
  if (!isQK) {
    char* const Pl = smem + LP1;           // P(NIT-1), (NIT-1)&1 == 1
#pragma unroll
    for (int qt = 0; qt < 2; ++qt)
#pragma unroll
      for (int ks = 0; ks < 4; ++ks) {
        const bf16x8 pa = *(const bf16x8*)(Pl + (qt * 32 + l31) * 128
                            + (((ks * 2 + l5) ^ (l31 & 7)) << 4));
#pragma unroll
        for (int dt = 0; dt < 4; ++dt)
          acc[qt][dt] = __builtin_amdgcn_mfma_f32_32x32x16_bf16(
              pa, vcur[dt * 4 + ks], acc[qt][dt], 0, 0, 0);
      }
    lred[jv * 64 + lane] = plsum;
    asm volatile("s_waitcnt lgkmcnt(0)" ::: "memory");
  }
  __builtin_amdgcn_s_barrier();
  __builtin_amdgcn_sched_barrier(0);
  if (isQK) return;

  const size_t rowb = (size_t)b * SEQ + qt0 * 64;
#pragma unroll
  for (int qt = 0; qt < 2; ++qt)
#pragma unroll
    for (int r = 0; r < 16; ++r) {
      const int q = qt * 32 + (r & 3) + 8 * (r >> 2) + 4 * l5;
      const float lq = lred[q] + lred[64 + q] + lred[128 + q] + lred[192 + q];
      const float sc = 0.2f / lq;
#pragma unroll
      for (int dt = 0; dt < 4; ++dt) {
        const int d = jv * 128 + dt * 32 + l31;
        const size_t gi = (rowb + q) * DIM + d;
        out[gi] = 1.2f * x[gi] - sc * acc[qt][dt][r];
      }
    }
}

extern "C" void kernel_launch(void* const* d_in, const int* in_sizes, int n_in,
                              void* d_out, int out_size, void* d_ws, size_t ws_size,
                              hipStream_t stream) {
  const float* x = (const float*)d_in[0];
  float* out = (float*)d_out;
  ushort_t* kg = (ushort_t*)d_ws;                                          // 16 MB
  ushort_t* vg = (ushort_t*)((char*)d_ws + (size_t)BATCH * SEQ * DIM * 2); // 16 MB

  k_prep<<<BATCH * SEQ / 32, 256, 0, stream>>>(x, kg, vg);
  (void)hipFuncSetAttribute((const void*)k_attn,
                            hipFuncAttributeMaxDynamicSharedMemorySize, LDS_TOTAL);
  k_attn<<<BATCH * SEQ / 64, 512, LDS_TOTAL, stream>>>(kg, vg, x, out);
}